// Round 19
// baseline (189.389 us; speedup 1.0000x reference)
//
#include <hip/hip_runtime.h>

#define B 8
#define S 1024
#define DM 512
#define H 8
#define D 64

typedef __attribute__((ext_vector_type(8))) short bf16x8;
typedef __attribute__((ext_vector_type(4))) float f32x4;

__device__ inline f32x4 mfma16(bf16x8 a, bf16x8 b, f32x4 c) {
  return __builtin_amdgcn_mfma_f32_16x16x32_bf16(a, b, c, 0, 0, 0);
}

__device__ inline ushort f2bf(float f) {
  uint u = __float_as_uint(f);
  u += 0x7fff + ((u >> 16) & 1);   // round-to-nearest-even
  return (ushort)(u >> 16);
}

__device__ inline float bf2f(ushort u) {
  return __uint_as_float(((uint)u) << 16);
}

// async global -> LDS, 16 bytes per lane (dest must be lane-linear!)
#define GLOAD16(gp, lp)                                                  \
  __builtin_amdgcn_global_load_lds(                                      \
      (const __attribute__((address_space(1))) void*)(gp),               \
      (__attribute__((address_space(3))) void*)(lp), 16, 0, 0)

// ---------------------------------------------------------------------------
// Cast x [B,S,DM] f32 -> bf16, vectorized.
// ---------------------------------------------------------------------------
__global__ __launch_bounds__(256) void cast_x_kernel(const float* __restrict__ x,
                                                     ushort* __restrict__ xbf) {
  int idx = blockIdx.x * 256 + threadIdx.x;         // one float4 per thread
  float4 v = *(const float4*)(x + (size_t)idx * 4);
  ushort4 o;
  o.x = f2bf(v.x); o.y = f2bf(v.y); o.z = f2bf(v.z); o.w = f2bf(v.w);
  *(ushort4*)(xbf + (size_t)idx * 4) = o;
}

// ---------------------------------------------------------------------------
// Weight prep: WT[f][m] = W{q,k,v}[h][m][d] (f = g*512 + h*64 + d), bf16.
//              WoT[m][f] = Wo[f][m], bf16.
// ---------------------------------------------------------------------------
__global__ __launch_bounds__(256) void prep_w_kernel(
    const float* __restrict__ Wq, const float* __restrict__ Wk,
    const float* __restrict__ Wv, const float* __restrict__ Wo,
    ushort* __restrict__ WT, ushort* __restrict__ WoT) {
  int idx = blockIdx.x * 256 + threadIdx.x;
  if (idx < 1536 * 512) {
    int f = idx >> 9, m = idx & 511;
    int g = f >> 9, fl = f & 511, h = fl >> 6, d = fl & 63;
    const float* W = (g == 0) ? Wq : (g == 1) ? Wk : Wv;
    WT[idx] = f2bf(W[((size_t)h * DM + m) * D + d]);
  } else {
    int i2 = idx - 1536 * 512;                      // [0, 512*512)
    int m = i2 >> 9, f = i2 & 511;
    WoT[(size_t)m * 512 + f] = f2bf(Wo[(size_t)f * DM + m]);
  }
}

// ---------------------------------------------------------------------------
// QKV GEMM: C[s][f] = sum_m xbf[s][m] * WT[f][m]   (M=8192, N=1536, K=512)
// R19: 64x64 tile (proven TLP) + global_load_lds width-16 staging (the one
// GEMM lever never isolated at this tile: R1/R3 bundled it with 128² which
// cost more TLP than the loads gained). LINEAR LDS (gload_lds requirement);
// frag-read bank conflicts accepted (same as m97 — staging is critical path).
// ---------------------------------------------------------------------------
__global__ __launch_bounds__(256) void qkv_gemm_kernel(
    const ushort* __restrict__ A, const ushort* __restrict__ Bm,
    ushort* __restrict__ qb, ushort* __restrict__ kb, ushort* __restrict__ vt) {
  __shared__ ushort As[64 * 64], Bs[64 * 64];       // 8 KB each, LINEAR
  const int tid = threadIdx.x;
  const int m0 = blockIdx.x * 64, n0 = blockIdx.y * 64;
  const int w = tid >> 6, l = tid & 63;
  const int r = l & 15, q = l >> 4;
  const int mh = (w >> 1) * 32, nh = (w & 1) * 32;

  f32x4 acc[2][2] = {};
  const int o0 = tid * 16;                          // staging byte offset

  for (int k0 = 0; k0 < 512; k0 += 64) {
    __syncthreads();                                // prev-iter LDS reads done
    #pragma unroll
    for (int j = 0; j < 2; ++j) {                   // 4 KB per round
      int o = j * 4096 + o0;                        // tile byte offset
      int row = o >> 7, cb = o & 127;               // 128 B per tile row
      GLOAD16(A + (size_t)(m0 + row) * 512 + k0 + (cb >> 1), &As[o >> 1]);
      GLOAD16(Bm + (size_t)(n0 + row) * 512 + k0 + (cb >> 1), &Bs[o >> 1]);
    }
    __syncthreads();                                // compiler drains vmcnt(0)
    #pragma unroll
    for (int kk = 0; kk < 64; kk += 32) {
      bf16x8 fa0 = *(const bf16x8*)&As[(mh + r) * 64 + kk + q * 8];
      bf16x8 fa1 = *(const bf16x8*)&As[(mh + 16 + r) * 64 + kk + q * 8];
      bf16x8 fb0 = *(const bf16x8*)&Bs[(nh + r) * 64 + kk + q * 8];
      bf16x8 fb1 = *(const bf16x8*)&Bs[(nh + 16 + r) * 64 + kk + q * 8];
      acc[0][0] = mfma16(fa0, fb0, acc[0][0]);
      acc[0][1] = mfma16(fa0, fb1, acc[0][1]);
      acc[1][0] = mfma16(fa1, fb0, acc[1][0]);
      acc[1][1] = mfma16(fa1, fb1, acc[1][1]);
    }
  }

  const int g = n0 >> 9;                            // 0=q 1=k 2=v, block-uniform
  #pragma unroll
  for (int mi = 0; mi < 2; ++mi)
    #pragma unroll
    for (int nj = 0; nj < 2; ++nj)
      #pragma unroll
      for (int i = 0; i < 4; ++i) {
        int row = m0 + mh + mi * 16 + q * 4 + i;    // global s-row
        int col = n0 + nh + nj * 16 + r;            // global f
        int bb = row >> 10, s = row & 1023;
        int fl = col & 511, h = fl >> 6, d = fl & 63;
        ushort val = f2bf(acc[mi][nj][i]);
        if (g == 0)
          qb[(((size_t)bb * H + h) * S + s) * D + d] = val;
        else if (g == 1)
          kb[(((size_t)bb * H + h) * S + s) * D + d] = val;
        else
          vt[(((size_t)bb * H + h) * D + d) * S + s] = val;
      }
}

// ---------------------------------------------------------------------------
// Attention v6 (R18 best, unchanged): swapped QK^T (mfma(K,Q) -> S^T),
// max-free softmax, 2-shuffle row sum, b64 P-writes, ONE barrier,
// full-line nt attn store from LDS, PV + concat per proven layout.
// ---------------------------------------------------------------------------
__global__ __launch_bounds__(256, 4) void attn_kernel(
    const ushort* __restrict__ qb, const ushort* __restrict__ kb,
    const ushort* __restrict__ vt, float* __restrict__ attn,
    ushort* __restrict__ concat) {
  __shared__ ushort Pl[16 * 1024];                  // 32 KB, swizzled bf16 P
  __shared__ float redsum[4][16];                   // 256 B
  const int tid = threadIdx.x;
  const int w = tid >> 6, l = tid & 63;
  const int r = l & 15, q = l >> 4;

  const int n = blockIdx.x;
  const int rank = n >> 3;
  const int bh = (n & 7) * 8 + (rank >> 6);         // locality map (R8)
  const int s0 = (rank & 63) * 16;

  // Q^T B-fragment: lane (r,q) holds Q[s0+r][q*8..+8] / [32+q*8..+8]
  const ushort* qp = qb + ((size_t)bh * S + s0) * D;
  bf16x8 qa0 = *(const bf16x8*)(qp + r * 64 + q * 8);
  bf16x8 qa1 = *(const bf16x8*)(qp + r * 64 + 32 + q * 8);

  // swapped scores + inline exp: p[kt][i] = exp(S[s0+r][w*256+kt*16+q*4+i]/8)
  const ushort* kp = kb + (size_t)bh * S * D;
  f32x4 p[16];
  float sm = 0.f;
  #pragma unroll
  for (int kt = 0; kt < 16; ++kt) {
    const ushort* kr = kp + (size_t)(w * 256 + kt * 16 + r) * 64 + q * 8;
    bf16x8 kf0 = *(const bf16x8*)kr;
    bf16x8 kf1 = *(const bf16x8*)(kr + 32);
    f32x4 a = {};
    a = mfma16(kf0, qa0, a);                        // SWAPPED: A=K, B=Q^T
    a = mfma16(kf1, qa1, a);
    #pragma unroll
    for (int i = 0; i < 4; ++i) {
      float e = __expf(a[i] * 0.125f);
      p[kt][i] = e;
      sm += e;
    }
  }

  // row-r sum: all 64 thread-values belong to row r -> 2-shuffle reduce
  sm += __shfl_xor(sm, 16);
  sm += __shfl_xor(sm, 32);
  if (q == 0) redsum[w][r] = sm;                    // wave-slice sum

  // P (unnormalized bf16) -> swizzled LDS, vectorized b64 per kt
  #pragma unroll
  for (int kt = 0; kt < 16; ++kt) {
    int col = w * 256 + kt * 16 + q * 4;            // 4-aligned; swz flips >=8
    ushort4 pk;
    pk.x = f2bf(p[kt][0]); pk.y = f2bf(p[kt][1]);
    pk.z = f2bf(p[kt][2]); pk.w = f2bf(p[kt][3]);
    *(ushort4*)&Pl[r * 1024 + (col ^ ((r & 7) << 3))] = pk;
  }
  __syncthreads();                                  // ONE barrier: redsum + Pl

  // per-row normalizers from redsum (p[] is dead past here -> regs free)
  float rvs[4];                                     // rows 4w..4w+3 (store)
  #pragma unroll
  for (int j = 0; j < 4; ++j) {
    int rr = w * 4 + j;
    rvs[j] = 1.0f / (redsum[0][rr] + redsum[1][rr] +
                     redsum[2][rr] + redsum[3][rr]);
  }
  float rpv[4];                                     // rows q*4+i (PV/concat)
  #pragma unroll
  for (int i = 0; i < 4; ++i) {
    int rr = q * 4 + i;
    rpv[i] = 1.0f / (redsum[0][rr] + redsum[1][rr] +
                     redsum[2][rr] + redsum[3][rr]);
  }

  // attn f32 store, full-line coalesced + nt (proven R7/R16 pattern):
  // wave w streams rows [4w, 4w+4), 4 chunks of 256 cols per row; per
  // instruction all 64 lanes write ONE row (lane li -> cols 4*li) = 1 KB.
  {
    float* ap = attn + ((size_t)bh * S + s0) * S;
    #pragma unroll
    for (int uu = 0; uu < 16; ++uu) {
      const int row = w * 4 + (uu >> 2);
      const int chunk = uu & 3;
      const int c = chunk * 256 + l * 4;
      const int swz = (row & 7) << 3;
      ushort4 p4 = *(const ushort4*)&Pl[row * 1024 + (c ^ swz)];
      const float rv = rvs[uu >> 2];
      f32x4 o;
      o.x = bf2f(p4.x) * rv;
      o.y = bf2f(p4.y) * rv;
      o.z = bf2f(p4.z) * rv;
      o.w = bf2f(p4.w) * rv;
      __builtin_nontemporal_store(o, (f32x4*)(ap + (size_t)row * S + c));
    }
  }

  // PV: wave w owns d-tile [w*16, w*16+16); A = P (LDS), B = V^T (global/L2)
  {
    const int d0 = w * 16;
    const ushort* vp = vt + ((size_t)bh * D + d0 + r) * S;
    f32x4 acc[4] = {};
    #pragma unroll
    for (int stp = 0; stp < 32; ++stp) {
      int t0 = stp * 32 + q * 8;
      bf16x8 pa = *(const bf16x8*)&Pl[r * 1024 + (t0 ^ ((r & 7) << 3))];
      bf16x8 vb = *(const bf16x8*)(vp + t0);
      acc[stp & 3] = mfma16(pa, vb, acc[stp & 3]);
    }
    f32x4 tot = acc[0] + acc[1] + acc[2] + acc[3];
    const int b = bh >> 3, h = bh & 7;
    #pragma unroll
    for (int i = 0; i < 4; ++i)
      concat[((size_t)b * S + s0 + q * 4 + i) * DM + h * D + d0 + r] =
          f2bf(tot[i] * rpv[i]);
  }
}

// ---------------------------------------------------------------------------
// Out-proj GEMM: z[s][m] = sum_f concat[s][f] * WoT[m][f]  (M=8192,N=512,K=512)
// R19: same gload_lds staging as qkv (64² tile, linear LDS).
// ---------------------------------------------------------------------------
__global__ __launch_bounds__(256) void outproj_gemm_kernel(
    const ushort* __restrict__ A, const ushort* __restrict__ Bm,
    float* __restrict__ z) {
  __shared__ ushort As[64 * 64], Bs[64 * 64];       // 8 KB each, LINEAR
  const int tid = threadIdx.x;
  const int m0 = blockIdx.x * 64, n0 = blockIdx.y * 64;
  const int w = tid >> 6, l = tid & 63;
  const int r = l & 15, q = l >> 4;
  const int mh = (w >> 1) * 32, nh = (w & 1) * 32;

  f32x4 acc[2][2] = {};
  const int o0 = tid * 16;

  for (int k0 = 0; k0 < 512; k0 += 64) {
    __syncthreads();
    #pragma unroll
    for (int j = 0; j < 2; ++j) {
      int o = j * 4096 + o0;
      int row = o >> 7, cb = o & 127;
      GLOAD16(A + (size_t)(m0 + row) * 512 + k0 + (cb >> 1), &As[o >> 1]);
      GLOAD16(Bm + (size_t)(n0 + row) * 512 + k0 + (cb >> 1), &Bs[o >> 1]);
    }
    __syncthreads();
    #pragma unroll
    for (int kk = 0; kk < 64; kk += 32) {
      bf16x8 fa0 = *(const bf16x8*)&As[(mh + r) * 64 + kk + q * 8];
      bf16x8 fa1 = *(const bf16x8*)&As[(mh + 16 + r) * 64 + kk + q * 8];
      bf16x8 fb0 = *(const bf16x8*)&Bs[(nh + r) * 64 + kk + q * 8];
      bf16x8 fb1 = *(const bf16x8*)&Bs[(nh + 16 + r) * 64 + kk + q * 8];
      acc[0][0] = mfma16(fa0, fb0, acc[0][0]);
      acc[0][1] = mfma16(fa0, fb1, acc[0][1]);
      acc[1][0] = mfma16(fa1, fb0, acc[1][0]);
      acc[1][1] = mfma16(fa1, fb1, acc[1][1]);
    }
  }

  #pragma unroll
  for (int mi = 0; mi < 2; ++mi)
    #pragma unroll
    for (int nj = 0; nj < 2; ++nj)
      #pragma unroll
      for (int i = 0; i < 4; ++i) {
        int row = m0 + mh + mi * 16 + q * 4 + i;
        int col = n0 + nh + nj * 16 + r;
        z[(size_t)row * DM + col] = acc[mi][nj][i];
      }
}

// ---------------------------------------------------------------------------
extern "C" void kernel_launch(void* const* d_in, const int* in_sizes, int n_in,
                              void* d_out, int out_size, void* d_ws, size_t ws_size,
                              hipStream_t stream) {
  const float* x  = (const float*)d_in[0];
  const float* Wq = (const float*)d_in[1];
  const float* Wk = (const float*)d_in[2];
  const float* Wv = (const float*)d_in[3];
  const float* Wo = (const float*)d_in[4];

  float* z    = (float*)d_out;                      // [B,S,DM]
  float* attn = z + (size_t)B * S * DM;             // [B,H,S,S]

  ushort* xbf    = (ushort*)d_ws;                   // [8192][512]
  ushort* WT     = xbf + (size_t)8192 * 512;        // [1536][512]
  ushort* WoT    = WT + (size_t)1536 * 512;         // [512][512]
  ushort* qb     = WoT + (size_t)512 * 512;         // [B,H,S,D]
  ushort* kb     = qb + (size_t)B * H * S * D;      // [B,H,S,D]
  ushort* vt     = kb + (size_t)B * H * S * D;      // [B,H,D,S]
  ushort* concat = vt + (size_t)B * H * S * D;      // [8192][512]

  cast_x_kernel<<<(B * S * DM / 4 + 255) / 256, 256, 0, stream>>>(x, xbf);
  prep_w_kernel<<<(1536 * 512 + 512 * 512) / 256, 256, 0, stream>>>(
      Wq, Wk, Wv, Wo, WT, WoT);
  qkv_gemm_kernel<<<dim3(8192 / 64, 1536 / 64), 256, 0, stream>>>(
      xbf, WT, qb, kb, vt);
  attn_kernel<<<4096, 256, 0, stream>>>(qb, kb, vt, attn, concat);
  outproj_gemm_kernel<<<dim3(8192 / 64, 512 / 64), 256, 0, stream>>>(
      concat, WoT, z);
}

// Round 20
// 181.615 us; speedup vs baseline: 1.0428x; 1.0428x over previous
//
#include <hip/hip_runtime.h>

#define B 8
#define S 1024
#define DM 512
#define H 8
#define D 64

typedef __attribute__((ext_vector_type(8))) short bf16x8;
typedef __attribute__((ext_vector_type(4))) float f32x4;

__device__ inline f32x4 mfma16(bf16x8 a, bf16x8 b, f32x4 c) {
  return __builtin_amdgcn_mfma_f32_16x16x32_bf16(a, b, c, 0, 0, 0);
}

__device__ inline ushort f2bf(float f) {
  uint u = __float_as_uint(f);
  u += 0x7fff + ((u >> 16) & 1);   // round-to-nearest-even
  return (ushort)(u >> 16);
}

__device__ inline float bf2f(ushort u) {
  return __uint_as_float(((uint)u) << 16);
}

// ---------------------------------------------------------------------------
// Merged prep (one launch, code paths identical to the proven cast_x +
// prep_w): blocks [0,4096) cast x f32->bf16 (float4/thread); blocks
// [4096,8192) transpose-pack W into WT / WoT.
// ---------------------------------------------------------------------------
__global__ __launch_bounds__(256) void prep_all_kernel(
    const float* __restrict__ x, const float* __restrict__ Wq,
    const float* __restrict__ Wk, const float* __restrict__ Wv,
    const float* __restrict__ Wo, ushort* __restrict__ xbf,
    ushort* __restrict__ WT, ushort* __restrict__ WoT) {
  const int bid = blockIdx.x;
  if (bid < 4096) {                                 // cast_x path (verbatim)
    int idx = bid * 256 + threadIdx.x;
    float4 v = *(const float4*)(x + (size_t)idx * 4);
    ushort4 o;
    o.x = f2bf(v.x); o.y = f2bf(v.y); o.z = f2bf(v.z); o.w = f2bf(v.w);
    *(ushort4*)(xbf + (size_t)idx * 4) = o;
  } else {                                          // prep_w path (verbatim)
    int idx = (bid - 4096) * 256 + threadIdx.x;
    if (idx < 1536 * 512) {
      int f = idx >> 9, m = idx & 511;
      int g = f >> 9, fl = f & 511, h = fl >> 6, d = fl & 63;
      const float* W = (g == 0) ? Wq : (g == 1) ? Wk : Wv;
      WT[idx] = f2bf(W[((size_t)h * DM + m) * D + d]);
    } else {
      int i2 = idx - 1536 * 512;                    // [0, 512*512)
      int m = i2 >> 9, f = i2 & 511;
      WoT[(size_t)m * 512 + f] = f2bf(Wo[(size_t)f * DM + m]);
    }
  }
}

// ---------------------------------------------------------------------------
// QKV GEMM: C[s][f] = sum_m xbf[s][m] * WT[f][m]   (M=8192, N=1536, K=512)
// 64x64 tile, 4 waves, REG-STAGED LDS (+8 pad) — R18/R0 proven form.
// R19 ledger: gload_lds at this tile = +4.4us (linear-LDS bank conflicts +
// vmcnt drain outweigh the 2-instr staging saving at only 8 K-steps).
// ---------------------------------------------------------------------------
__global__ __launch_bounds__(256) void qkv_gemm_kernel(
    const ushort* __restrict__ A, const ushort* __restrict__ Bm,
    ushort* __restrict__ qb, ushort* __restrict__ kb, ushort* __restrict__ vt) {
  __shared__ ushort As[64][72], Bs[64][72];         // +16B pad per row
  const int tid = threadIdx.x;
  const int m0 = blockIdx.x * 64, n0 = blockIdx.y * 64;
  const int w = tid >> 6, l = tid & 63;
  const int r = l & 15, q = l >> 4;
  const int mh = (w >> 1) * 32, nh = (w & 1) * 32;

  f32x4 acc[2][2] = {};
  const int srow = tid >> 2, sco = (tid & 3) * 16;  // staging: 32B per thread

  for (int k0 = 0; k0 < 512; k0 += 64) {
    const ushort* ap = A + (size_t)(m0 + srow) * 512 + k0 + sco;
    const ushort* bp = Bm + (size_t)(n0 + srow) * 512 + k0 + sco;
    uint4 a0 = *(const uint4*)ap;
    uint4 a1 = *(const uint4*)(ap + 8);
    uint4 b0 = *(const uint4*)bp;
    uint4 b1 = *(const uint4*)(bp + 8);
    __syncthreads();
    *(uint4*)&As[srow][sco] = a0;
    *(uint4*)&As[srow][sco + 8] = a1;
    *(uint4*)&Bs[srow][sco] = b0;
    *(uint4*)&Bs[srow][sco + 8] = b1;
    __syncthreads();
    #pragma unroll
    for (int kk = 0; kk < 64; kk += 32) {
      bf16x8 fa0 = *(const bf16x8*)&As[mh + r][kk + q * 8];
      bf16x8 fa1 = *(const bf16x8*)&As[mh + 16 + r][kk + q * 8];
      bf16x8 fb0 = *(const bf16x8*)&Bs[nh + r][kk + q * 8];
      bf16x8 fb1 = *(const bf16x8*)&Bs[nh + 16 + r][kk + q * 8];
      acc[0][0] = mfma16(fa0, fb0, acc[0][0]);
      acc[0][1] = mfma16(fa0, fb1, acc[0][1]);
      acc[1][0] = mfma16(fa1, fb0, acc[1][0]);
      acc[1][1] = mfma16(fa1, fb1, acc[1][1]);
    }
  }

  const int g = n0 >> 9;                            // 0=q 1=k 2=v, block-uniform
  #pragma unroll
  for (int mi = 0; mi < 2; ++mi)
    #pragma unroll
    for (int nj = 0; nj < 2; ++nj)
      #pragma unroll
      for (int i = 0; i < 4; ++i) {
        int row = m0 + mh + mi * 16 + q * 4 + i;    // global s-row
        int col = n0 + nh + nj * 16 + r;            // global f
        int bb = row >> 10, s = row & 1023;
        int fl = col & 511, h = fl >> 6, d = fl & 63;
        ushort val = f2bf(acc[mi][nj][i]);
        if (g == 0)
          qb[(((size_t)bb * H + h) * S + s) * D + d] = val;
        else if (g == 1)
          kb[(((size_t)bb * H + h) * S + s) * D + d] = val;
        else
          vt[(((size_t)bb * H + h) * D + d) * S + s] = val;
      }
}

// ---------------------------------------------------------------------------
// Attention v6 (R18 best, verbatim): swapped QK^T (mfma(K,Q) -> S^T),
// max-free softmax, 2-shuffle row sum, b64 P-writes, ONE barrier,
// full-line nt attn store from LDS, PV + concat per proven layout.
// ---------------------------------------------------------------------------
__global__ __launch_bounds__(256, 4) void attn_kernel(
    const ushort* __restrict__ qb, const ushort* __restrict__ kb,
    const ushort* __restrict__ vt, float* __restrict__ attn,
    ushort* __restrict__ concat) {
  __shared__ ushort Pl[16 * 1024];                  // 32 KB, swizzled bf16 P
  __shared__ float redsum[4][16];                   // 256 B
  const int tid = threadIdx.x;
  const int w = tid >> 6, l = tid & 63;
  const int r = l & 15, q = l >> 4;

  const int n = blockIdx.x;
  const int rank = n >> 3;
  const int bh = (n & 7) * 8 + (rank >> 6);         // locality map (R8)
  const int s0 = (rank & 63) * 16;

  // Q^T B-fragment: lane (r,q) holds Q[s0+r][q*8..+8] / [32+q*8..+8]
  const ushort* qp = qb + ((size_t)bh * S + s0) * D;
  bf16x8 qa0 = *(const bf16x8*)(qp + r * 64 + q * 8);
  bf16x8 qa1 = *(const bf16x8*)(qp + r * 64 + 32 + q * 8);

  // swapped scores + inline exp: p[kt][i] = exp(S[s0+r][w*256+kt*16+q*4+i]/8)
  const ushort* kp = kb + (size_t)bh * S * D;
  f32x4 p[16];
  float sm = 0.f;
  #pragma unroll
  for (int kt = 0; kt < 16; ++kt) {
    const ushort* kr = kp + (size_t)(w * 256 + kt * 16 + r) * 64 + q * 8;
    bf16x8 kf0 = *(const bf16x8*)kr;
    bf16x8 kf1 = *(const bf16x8*)(kr + 32);
    f32x4 a = {};
    a = mfma16(kf0, qa0, a);                        // SWAPPED: A=K, B=Q^T
    a = mfma16(kf1, qa1, a);
    #pragma unroll
    for (int i = 0; i < 4; ++i) {
      float e = __expf(a[i] * 0.125f);
      p[kt][i] = e;
      sm += e;
    }
  }

  // row-r sum: all 64 thread-values belong to row r -> 2-shuffle reduce
  sm += __shfl_xor(sm, 16);
  sm += __shfl_xor(sm, 32);
  if (q == 0) redsum[w][r] = sm;                    // wave-slice sum

  // P (unnormalized bf16) -> swizzled LDS, vectorized b64 per kt
  #pragma unroll
  for (int kt = 0; kt < 16; ++kt) {
    int col = w * 256 + kt * 16 + q * 4;            // 4-aligned; swz flips >=8
    ushort4 pk;
    pk.x = f2bf(p[kt][0]); pk.y = f2bf(p[kt][1]);
    pk.z = f2bf(p[kt][2]); pk.w = f2bf(p[kt][3]);
    *(ushort4*)&Pl[r * 1024 + (col ^ ((r & 7) << 3))] = pk;
  }
  __syncthreads();                                  // ONE barrier: redsum + Pl

  // per-row normalizers from redsum (p[] is dead past here -> regs free)
  float rvs[4];                                     // rows 4w..4w+3 (store)
  #pragma unroll
  for (int j = 0; j < 4; ++j) {
    int rr = w * 4 + j;
    rvs[j] = 1.0f / (redsum[0][rr] + redsum[1][rr] +
                     redsum[2][rr] + redsum[3][rr]);
  }
  float rpv[4];                                     // rows q*4+i (PV/concat)
  #pragma unroll
  for (int i = 0; i < 4; ++i) {
    int rr = q * 4 + i;
    rpv[i] = 1.0f / (redsum[0][rr] + redsum[1][rr] +
                     redsum[2][rr] + redsum[3][rr]);
  }

  // attn f32 store, full-line coalesced + nt (proven R7/R16 pattern):
  // wave w streams rows [4w, 4w+4), 4 chunks of 256 cols per row; per
  // instruction all 64 lanes write ONE row (lane li -> cols 4*li) = 1 KB.
  {
    float* ap = attn + ((size_t)bh * S + s0) * S;
    #pragma unroll
    for (int uu = 0; uu < 16; ++uu) {
      const int row = w * 4 + (uu >> 2);
      const int chunk = uu & 3;
      const int c = chunk * 256 + l * 4;
      const int swz = (row & 7) << 3;
      ushort4 p4 = *(const ushort4*)&Pl[row * 1024 + (c ^ swz)];
      const float rv = rvs[uu >> 2];
      f32x4 o;
      o.x = bf2f(p4.x) * rv;
      o.y = bf2f(p4.y) * rv;
      o.z = bf2f(p4.z) * rv;
      o.w = bf2f(p4.w) * rv;
      __builtin_nontemporal_store(o, (f32x4*)(ap + (size_t)row * S + c));
    }
  }

  // PV: wave w owns d-tile [w*16, w*16+16); A = P (LDS), B = V^T (global/L2)
  {
    const int d0 = w * 16;
    const ushort* vp = vt + ((size_t)bh * D + d0 + r) * S;
    f32x4 acc[4] = {};
    #pragma unroll
    for (int stp = 0; stp < 32; ++stp) {
      int t0 = stp * 32 + q * 8;
      bf16x8 pa = *(const bf16x8*)&Pl[r * 1024 + (t0 ^ ((r & 7) << 3))];
      bf16x8 vb = *(const bf16x8*)(vp + t0);
      acc[stp & 3] = mfma16(pa, vb, acc[stp & 3]);
    }
    f32x4 tot = acc[0] + acc[1] + acc[2] + acc[3];
    const int b = bh >> 3, h = bh & 7;
    #pragma unroll
    for (int i = 0; i < 4; ++i)
      concat[((size_t)b * S + s0 + q * 4 + i) * DM + h * D + d0 + r] =
          f2bf(tot[i] * rpv[i]);
  }
}

// ---------------------------------------------------------------------------
// Out-proj GEMM: z[s][m] = sum_f concat[s][f] * WoT[m][f]  (M=8192,N=512,K=512)
// 64x64 tile, reg-staged (R18/R0 proven form).
// ---------------------------------------------------------------------------
__global__ __launch_bounds__(256) void outproj_gemm_kernel(
    const ushort* __restrict__ A, const ushort* __restrict__ Bm,
    float* __restrict__ z) {
  __shared__ ushort As[64][72], Bs[64][72];
  const int tid = threadIdx.x;
  const int m0 = blockIdx.x * 64, n0 = blockIdx.y * 64;
  const int w = tid >> 6, l = tid & 63;
  const int r = l & 15, q = l >> 4;
  const int mh = (w >> 1) * 32, nh = (w & 1) * 32;

  f32x4 acc[2][2] = {};
  const int srow = tid >> 2, sco = (tid & 3) * 16;

  for (int k0 = 0; k0 < 512; k0 += 64) {
    const ushort* ap = A + (size_t)(m0 + srow) * 512 + k0 + sco;
    const ushort* bp = Bm + (size_t)(n0 + srow) * 512 + k0 + sco;
    uint4 a0 = *(const uint4*)ap;
    uint4 a1 = *(const uint4*)(ap + 8);
    uint4 b0 = *(const uint4*)bp;
    uint4 b1 = *(const uint4*)(bp + 8);
    __syncthreads();
    *(uint4*)&As[srow][sco] = a0;
    *(uint4*)&As[srow][sco + 8] = a1;
    *(uint4*)&Bs[srow][sco] = b0;
    *(uint4*)&Bs[srow][sco + 8] = b1;
    __syncthreads();
    #pragma unroll
    for (int kk = 0; kk < 64; kk += 32) {
      bf16x8 fa0 = *(const bf16x8*)&As[mh + r][kk + q * 8];
      bf16x8 fa1 = *(const bf16x8*)&As[mh + 16 + r][kk + q * 8];
      bf16x8 fb0 = *(const bf16x8*)&Bs[nh + r][kk + q * 8];
      bf16x8 fb1 = *(const bf16x8*)&Bs[nh + 16 + r][kk + q * 8];
      acc[0][0] = mfma16(fa0, fb0, acc[0][0]);
      acc[0][1] = mfma16(fa0, fb1, acc[0][1]);
      acc[1][0] = mfma16(fa1, fb0, acc[1][0]);
      acc[1][1] = mfma16(fa1, fb1, acc[1][1]);
    }
  }

  #pragma unroll
  for (int mi = 0; mi < 2; ++mi)
    #pragma unroll
    for (int nj = 0; nj < 2; ++nj)
      #pragma unroll
      for (int i = 0; i < 4; ++i) {
        int row = m0 + mh + mi * 16 + q * 4 + i;
        int col = n0 + nh + nj * 16 + r;
        z[(size_t)row * DM + col] = acc[mi][nj][i];
      }
}

// ---------------------------------------------------------------------------
extern "C" void kernel_launch(void* const* d_in, const int* in_sizes, int n_in,
                              void* d_out, int out_size, void* d_ws, size_t ws_size,
                              hipStream_t stream) {
  const float* x  = (const float*)d_in[0];
  const float* Wq = (const float*)d_in[1];
  const float* Wk = (const float*)d_in[2];
  const float* Wv = (const float*)d_in[3];
  const float* Wo = (const float*)d_in[4];

  float* z    = (float*)d_out;                      // [B,S,DM]
  float* attn = z + (size_t)B * S * DM;             // [B,H,S,S]

  ushort* xbf    = (ushort*)d_ws;                   // [8192][512]
  ushort* WT     = xbf + (size_t)8192 * 512;        // [1536][512]
  ushort* WoT    = WT + (size_t)1536 * 512;         // [512][512]
  ushort* qb     = WoT + (size_t)512 * 512;         // [B,H,S,D]
  ushort* kb     = qb + (size_t)B * H * S * D;      // [B,H,S,D]
  ushort* vt     = kb + (size_t)B * H * S * D;      // [B,H,D,S]
  ushort* concat = vt + (size_t)B * H * S * D;      // [8192][512]

  prep_all_kernel<<<8192, 256, 0, stream>>>(x, Wq, Wk, Wv, Wo, xbf, WT, WoT);
  qkv_gemm_kernel<<<dim3(8192 / 64, 1536 / 64), 256, 0, stream>>>(
      xbf, WT, qb, kb, vt);
  attn_kernel<<<4096, 256, 0, stream>>>(qb, kb, vt, attn, concat);
  outproj_gemm_kernel<<<dim3(8192 / 64, 512 / 64), 256, 0, stream>>>(
      concat, WoT, z);
}